// Round 4
// baseline (104.655 us; speedup 1.0000x reference)
//
#include <hip/hip_runtime.h>
#include <stdint.h>

#define NCLS 80
#define BGI 80
#define BB 16
#define NGT 32
#define MM 33600
#define EPSF 1e-9f
#define INF_KEY 0xffffffffffffffffull

// IoU exactly mirroring reference pairwise_iou op order; no FMA contraction.
__device__ __forceinline__ float iou_f(const float4 b1, const float4 b2) {
#pragma clang fp contract(off)
  float ltx = fmaxf(b1.x, b2.x);
  float lty = fmaxf(b1.y, b2.y);
  float rbx = fminf(b1.z, b2.z);
  float rby = fminf(b1.w, b2.w);
  float iw = fmaxf(rbx - ltx, 0.0f);
  float ih = fmaxf(rby - lty, 0.0f);
  float inter = iw * ih;
  float a1 = (b1.z - b1.x) * (b1.w - b1.y);
  float a2 = (b2.z - b2.x) * (b2.w - b2.y);
  return inter / (a1 + a2 - inter + EPSF);
}

// P0: precompute anchor centers (same op order as reference anchor_points)
// and zero the per-(b,anchor) candidate counters. 2100*256 == 537600 exact.
__global__ __launch_bounds__(256) void k_prep(
    const float4* __restrict__ anchors, float2* __restrict__ centers,
    unsigned int* __restrict__ cnt) {
#pragma clang fp contract(off)
  const int i = blockIdx.x * 256 + threadIdx.x;
  if (i < MM) {
    const float4 ab = anchors[i];
    centers[i] = make_float2((ab.x + ab.z) * 0.5f, (ab.y + ab.w) * 0.5f);
  }
  cnt[i] = 0u;
}

// K1: one 1024-thread block (16 waves) per (b,g). Per-lane sorted top-9 over
// a ~33-element strided slice, per-wave 9-pop u64 butterfly merge -> LDS,
// one barrier, wave 0 merges the 16 sorted lists per level (register heads),
// then computes threshold stats and scatters positives.
__global__ __launch_bounds__(1024) void k_topk(
    const float4* __restrict__ anchors, const float2* __restrict__ centers,
    const float4* __restrict__ gtb, const float* __restrict__ maskgt,
    unsigned int* __restrict__ cnt, unsigned int* __restrict__ gidx) {
#pragma clang fp contract(off)
  const int pair = blockIdx.x;            // b*32+g
  if (maskgt[pair] == 0.0f) return;       // masked gt contributes nothing
  const int b = pair >> 5;
  const int g = pair & 31;
  const int tid = threadIdx.x;
  const int lane = tid & 63;
  const int wid = tid >> 6;
  const float4 gb = gtb[pair];
  const float gcx = (gb.x + gb.z) * 0.5f;
  const float gcy = (gb.y + gb.w) * 0.5f;

  __shared__ unsigned long long smem[3][16][9];  // per-level per-wave top9

  const int LSTART[3] = {0, 25600, 32000};
  const int LLEN[3]   = {25600, 6400, 1600};

#pragma unroll
  for (int lev = 0; lev < 3; ++lev) {
    float dd[9];
    unsigned int ii[9];
#pragma unroll
    for (int q = 0; q < 9; ++q) { dd[q] = 3.4e38f; ii[q] = 0u; }
    const int start = LSTART[lev];
    const int len = LLEN[lev];
    for (int j = tid; j < len; j += 1024) {
      const float2 ac = centers[start + j];
      const float dx = gcx - ac.x;
      const float dy = gcy - ac.y;
      const float dist = sqrtf(dx * dx + dy * dy);
      if (dist < dd[8]) {  // strict: keeps earliest index among equals
        float curd = dist;
        unsigned int curi = (unsigned int)(start + j);
#pragma unroll
        for (int q = 0; q < 9; ++q) {  // static-indexed bubble insertion
          const bool less = curd < dd[q];
          const float td = less ? dd[q] : curd;
          const unsigned int ti = less ? ii[q] : curi;
          dd[q] = less ? curd : dd[q];
          ii[q] = less ? curi : ii[q];
          curd = td; curi = ti;
        }
      }
    }
    // per-wave merge: 9 pops of 64-lane min over packed (dist,idx) keys.
    // Keys unique (idx in low bits) -> exactly one lane pops per step.
#pragma unroll
    for (int t = 0; t < 9; ++t) {
      const unsigned long long key =
          ((unsigned long long)__float_as_uint(dd[0]) << 32) |
          (unsigned long long)ii[0];
      unsigned long long mn = key;
#pragma unroll
      for (int s = 32; s >= 1; s >>= 1) {
        const unsigned long long o = __shfl_xor(mn, s, 64);
        mn = (o < mn) ? o : mn;
      }
      if (lane == 0) smem[lev][wid][t] = mn;
      if (key == mn) {
#pragma unroll
        for (int q = 0; q < 8; ++q) { dd[q] = dd[q + 1]; ii[q] = ii[q + 1]; }
        dd[8] = 3.4e38f; ii[8] = 0u;
      }
    }
  }

  __syncthreads();
  if (wid != 0) return;  // only wave 0 continues (no more barriers)

  // wave 0: merge 16 sorted lists of 9 per level; candidate (lev*9+t) -> lane.
  unsigned int mycand = 0;
#pragma unroll
  for (int lev = 0; lev < 3; ++lev) {
    unsigned long long lst[9];
#pragma unroll
    for (int q = 0; q < 9; ++q)
      lst[q] = (lane < 16) ? smem[lev][lane][q] : INF_KEY;
#pragma unroll
    for (int t = 0; t < 9; ++t) {
      unsigned long long mn = lst[0];
#pragma unroll
      for (int s = 8; s >= 1; s >>= 1) {  // butterfly over 16-lane group
        const unsigned long long o = __shfl_xor(mn, s, 64);
        mn = (o < mn) ? o : mn;
      }
      const unsigned long long mnb = __shfl(mn, 0, 64);  // broadcast to all
      if (lane == lev * 9 + t) mycand = (unsigned int)(mnb & 0xffffffffu);
      if (lst[0] == mnb) {  // unique winner advances its list
#pragma unroll
        for (int q = 0; q < 8; ++q) lst[q] = lst[q + 1];
        lst[8] = INF_KEY;
      }
    }
  }

  // candidate IoUs + inside-gt test (lanes 0..26)
  float ov = 0.0f;
  bool inside = false;
  if (lane < 27) {
    const float4 ab = anchors[mycand];
    ov = iou_f(gb, ab);
    const float2 ac = centers[mycand];
    const float m1 = fminf(fminf(ac.x - gb.x, ac.y - gb.y),
                           fminf(gb.z - ac.x, gb.w - ac.y));
    inside = m1 > EPSF;
  }
  // thr = mean + std(ddof=1) over the 27 gathered IoUs
  float s = (lane < 27) ? ov : 0.0f;
#pragma unroll
  for (int sft = 32; sft >= 1; sft >>= 1) s += __shfl_xor(s, sft, 64);
  const float mean = s / 27.0f;
  float dev = (lane < 27) ? (ov - mean) : 0.0f;
  float s2 = dev * dev;
#pragma unroll
  for (int sft = 32; sft >= 1; sft >>= 1) s2 += __shfl_xor(s2, sft, 64);
  const float thr = mean + sqrtf(s2 / 26.0f);

  if (lane < 27 && inside && ov > thr) {
    atomicAdd(&cnt[b * MM + (int)mycand], 1u);
    gidx[b * MM + (int)mycand] = (unsigned int)g;  // only read when cnt==1
  }
}

// B1+B2 fused: each block owns 64 rows of one batch. Threads 0..63 resolve
// the assignment (labels/bbox/fg) and stash (label,iou) in LDS; then all 320
// threads stream the 64x80 one-hot*iou score slab as coalesced float4.
__global__ __launch_bounds__(320) void k_out(
    const float4* __restrict__ anchors, const float4* __restrict__ gtb,
    const int* __restrict__ glabels, const float4* __restrict__ predb,
    const unsigned int* __restrict__ cnt, const unsigned int* __restrict__ gidx,
    float* __restrict__ out_labels, float4* __restrict__ out_bbox,
    float* __restrict__ out_fg, float4* __restrict__ out_scores) {
  const int t = threadIdx.x;
  const int b = blockIdx.y;
  const int row0 = blockIdx.x * 64;  // 525*64 == 33600 exact

  __shared__ int s_lbl[64];
  __shared__ float s_iou[64];

  if (t < 64) {
    const int a = row0 + t;
    const int i = b * MM + a;
    const unsigned int c = cnt[i];
    int g = 0;
    const bool fg = (c != 0u);
    if (c == 1u) {
      g = (int)gidx[i];
    } else if (c > 1u) {
      // reference: column replaced by one_hot(argmax_g overlaps) — includes
      // masked gts; first-max tie-break like jnp.argmax.
      const float4 ab = anchors[a];
      float best = -1.0f;
      for (int gg = 0; gg < NGT; ++gg) {
        const float ovv = iou_f(gtb[b * NGT + gg], ab);
        if (ovv > best) { best = ovv; g = gg; }
      }
    }
    const int lbl = fg ? glabels[b * NGT + g] : BGI;
    out_labels[i] = (float)lbl;
    out_bbox[i] = gtb[b * NGT + g];  // !fg -> g==0 (argmax of zeros)
    const float io = fg ? iou_f(gtb[b * NGT + g], predb[i]) : 0.0f;
    out_fg[i] = fg ? 1.0f : 0.0f;
    s_lbl[t] = fg ? lbl : -1;
    s_iou[t] = io;
  }
  __syncthreads();

  // 64 rows * 20 float4 = 1280 float4; 320 threads * 4 iters, coalesced.
  const size_t base = ((size_t)b * MM + row0) * 20;
#pragma unroll
  for (int it = 0; it < 4; ++it) {
    const int idx = it * 320 + t;
    const int row = idx / 20;          // magic-mul, compile-time const 20
    const int c4 = idx - row * 20;
    const int lbl = s_lbl[row];
    const float io = s_iou[row];
    const int cb = c4 * 4;
    float4 v;
    v.x = (lbl == cb) ? io : 0.0f;
    v.y = (lbl == cb + 1) ? io : 0.0f;
    v.z = (lbl == cb + 2) ? io : 0.0f;
    v.w = (lbl == cb + 3) ? io : 0.0f;
    out_scores[base + idx] = v;
  }
}

extern "C" void kernel_launch(void* const* d_in, const int* in_sizes, int n_in,
                              void* d_out, int out_size, void* d_ws, size_t ws_size,
                              hipStream_t stream) {
  // Identify inputs by size (robust to how the n_level tuple is passed).
  const float* anchors = nullptr;
  const float* gtb = nullptr;
  const int* glab = nullptr;
  const float* maskgt = nullptr;
  const float* predb = nullptr;
  int seen512 = 0;
  for (int i = 0; i < n_in; ++i) {
    const int sz = in_sizes[i];
    if (sz == 134400 && !anchors) anchors = (const float*)d_in[i];
    else if (sz == 2048 && !gtb) gtb = (const float*)d_in[i];
    else if (sz == 512) {
      if (seen512++ == 0) glab = (const int*)d_in[i];
      else maskgt = (const float*)d_in[i];
    } else if (sz == 2150400 && !predb) predb = (const float*)d_in[i];
  }
  if (!anchors || !gtb || !glab || !maskgt || !predb) return;  // defensive

  float* out = (float*)d_out;
  float* out_labels = out;                          // [B*M]
  float4* out_bbox = (float4*)(out + 537600);       // [B*M][4]
  float4* out_scores = (float4*)(out + 2688000);    // [B*M][80]
  float* out_fg = out + 45696000;                   // [B*M]

  unsigned int* cnt = (unsigned int*)d_ws;          // [B*M]
  unsigned int* gidx = cnt + 537600;                // [B*M]
  float2* centers = (float2*)(gidx + 537600);       // [M]

  k_prep<<<dim3(2100), dim3(256), 0, stream>>>(
      (const float4*)anchors, centers, cnt);

  k_topk<<<dim3(BB * NGT), dim3(1024), 0, stream>>>(
      (const float4*)anchors, centers, (const float4*)gtb, maskgt, cnt, gidx);

  k_out<<<dim3(525, BB), dim3(320), 0, stream>>>(
      (const float4*)anchors, (const float4*)gtb, glab, (const float4*)predb,
      cnt, gidx, out_labels, out_bbox, out_fg, out_scores);
}

// Round 5
// 70.258 us; speedup vs baseline: 1.4896x; 1.4896x over previous
//
#include <hip/hip_runtime.h>
#include <stdint.h>

#define NCLS 80
#define BGI 80
#define BB 16
#define NGT 32
#define MM 33600
#define EPSF 1e-9f
#define CAP 1024

// IoU exactly mirroring reference pairwise_iou op order; no FMA contraction.
__device__ __forceinline__ float iou_f(const float4 b1, const float4 b2) {
#pragma clang fp contract(off)
  float ltx = fmaxf(b1.x, b2.x);
  float lty = fmaxf(b1.y, b2.y);
  float rbx = fminf(b1.z, b2.z);
  float rby = fminf(b1.w, b2.w);
  float iw = fmaxf(rbx - ltx, 0.0f);
  float ih = fmaxf(rby - lty, 0.0f);
  float inter = iw * ih;
  float a1 = (b1.z - b1.x) * (b1.w - b1.y);
  float a2 = (b2.z - b2.x) * (b2.w - b2.y);
  return inter / (a1 + a2 - inter + EPSF);
}

// P0: precompute anchor centers (same op order as reference anchor_points)
// and zero the per-(b,anchor) candidate counters. 2100*256 == 537600 exact.
__global__ __launch_bounds__(256) void k_prep(
    const float4* __restrict__ anchors, float2* __restrict__ centers,
    unsigned int* __restrict__ cnt) {
#pragma clang fp contract(off)
  const int i = blockIdx.x * 256 + threadIdx.x;
  if (i < MM) {
    const float4 ab = anchors[i];
    centers[i] = make_float2((ab.x + ab.z) * 0.5f, (ab.y + ab.w) * 0.5f);
  }
  cnt[i] = 0u;
}

// K1: one 1024-thread block per (b,g). Bound-then-rank top-9 per level:
//  pass1: per-thread min -> 16 wave minima -> T = 9th smallest (upper bound
//         on the true 9th distance, proof: <9 elements can be < K9).
//  pass2: collect all keys (distbits<<32|idx) with dist<=T into LDS (m>=9).
//  rank:  key's rank = #smaller keys; ranks unique; rank<9 -> winner.
// No serial pops, no cross-lane shuffles for the merge. Exact top_k tie
// semantics (equal dist -> smaller index) via the packed key.
__global__ __launch_bounds__(1024) void k_topk(
    const float4* __restrict__ anchors, const float2* __restrict__ centers,
    const float4* __restrict__ gtb, const float* __restrict__ maskgt,
    unsigned int* __restrict__ cnt, unsigned int* __restrict__ gidx) {
#pragma clang fp contract(off)
  const int pair = blockIdx.x;            // b*32+g
  if (maskgt[pair] == 0.0f) return;       // masked gt contributes nothing
  const int b = pair >> 5;
  const int g = pair & 31;
  const int tid = threadIdx.x;
  const int lane = tid & 63;
  const int wid = tid >> 6;
  const float4 gb = gtb[pair];
  const float gcx = (gb.x + gb.z) * 0.5f;
  const float gcy = (gb.y + gb.w) * 0.5f;

  __shared__ unsigned long long buf[CAP];
  __shared__ unsigned long long winners[27];
  __shared__ float s_wmin[16];
  __shared__ float s_T;
  __shared__ unsigned int s_cnt;

  const int LSTART[3] = {0, 25600, 32000};
  const int LLEN[3]   = {25600, 6400, 1600};

#pragma unroll
  for (int lev = 0; lev < 3; ++lev) {
    const int start = LSTART[lev];
    const int len = LLEN[lev];

    // pass 1: branch-free per-thread min
    float mymin = 3.4e38f;
    for (int j = tid; j < len; j += 1024) {
      const float2 ac = centers[start + j];
      const float dx = gcx - ac.x;
      const float dy = gcy - ac.y;
      mymin = fminf(mymin, sqrtf(dx * dx + dy * dy));
    }
#pragma unroll
    for (int s = 32; s >= 1; s >>= 1)
      mymin = fminf(mymin, __shfl_xor(mymin, s, 64));
    if (lane == 0) s_wmin[wid] = mymin;
    if (tid == 0) s_cnt = 0u;
    __syncthreads();

    // T = 9th smallest of the 16 wave minima (rank-compute, wave 0 only)
    if (wid == 0 && lane < 16) {
      const float v = s_wmin[lane];
      int r = 0;
#pragma unroll
      for (int q = 0; q < 16; ++q) {
        const float o = s_wmin[q];
        r += (o < v) || (o == v && q < lane);
      }
      if (r == 8) s_T = v;  // unique lane
    }
    __syncthreads();
    const float T = s_T;

    // pass 2: collect candidates <= T (identical dist expression as pass 1)
    for (int j = tid; j < len; j += 1024) {
      const float2 ac = centers[start + j];
      const float dx = gcx - ac.x;
      const float dy = gcy - ac.y;
      const float dist = sqrtf(dx * dx + dy * dy);
      if (dist <= T) {
        const unsigned int p = atomicAdd(&s_cnt, 1u);
        if (p < CAP)
          buf[p] = ((unsigned long long)__float_as_uint(dist) << 32) |
                   (unsigned long long)(unsigned int)(start + j);
      }
    }
    __syncthreads();
    const int m = (int)min(s_cnt, (unsigned int)CAP);

    // rank-select: exactly 9 winners (keys unique -> ranks unique)
    for (int i = tid; i < m; i += 1024) {
      const unsigned long long k = buf[i];
      int r = 0;
      for (int q = 0; q < m; ++q) r += (buf[q] < k);
      if (r < 9) winners[lev * 9 + r] = k;
    }
    __syncthreads();
  }

  if (wid != 0) return;  // wave 0 finishes; no more barriers

  unsigned int mycand = 0;
  if (lane < 27) mycand = (unsigned int)(winners[lane] & 0xffffffffu);

  // candidate IoUs + inside-gt test (lanes 0..26)
  float ov = 0.0f;
  bool inside = false;
  if (lane < 27) {
    const float4 ab = anchors[mycand];
    ov = iou_f(gb, ab);
    const float2 ac = centers[mycand];
    const float m1 = fminf(fminf(ac.x - gb.x, ac.y - gb.y),
                           fminf(gb.z - ac.x, gb.w - ac.y));
    inside = m1 > EPSF;
  }
  // thr = mean + std(ddof=1) over the 27 gathered IoUs
  float s = (lane < 27) ? ov : 0.0f;
#pragma unroll
  for (int sft = 32; sft >= 1; sft >>= 1) s += __shfl_xor(s, sft, 64);
  const float mean = s / 27.0f;
  float dev = (lane < 27) ? (ov - mean) : 0.0f;
  float s2 = dev * dev;
#pragma unroll
  for (int sft = 32; sft >= 1; sft >>= 1) s2 += __shfl_xor(s2, sft, 64);
  const float thr = mean + sqrtf(s2 / 26.0f);

  if (lane < 27 && inside && ov > thr) {
    atomicAdd(&cnt[b * MM + (int)mycand], 1u);
    gidx[b * MM + (int)mycand] = (unsigned int)g;  // only read when cnt==1
  }
}

// B1+B2 fused: each block owns 64 rows of one batch. Threads 0..63 resolve
// the assignment (labels/bbox/fg) and stash (label,iou) in LDS; then all 320
// threads stream the 64x80 one-hot*iou score slab as coalesced float4.
__global__ __launch_bounds__(320) void k_out(
    const float4* __restrict__ anchors, const float4* __restrict__ gtb,
    const int* __restrict__ glabels, const float4* __restrict__ predb,
    const unsigned int* __restrict__ cnt, const unsigned int* __restrict__ gidx,
    float* __restrict__ out_labels, float4* __restrict__ out_bbox,
    float* __restrict__ out_fg, float4* __restrict__ out_scores) {
  const int t = threadIdx.x;
  const int b = blockIdx.y;
  const int row0 = blockIdx.x * 64;  // 525*64 == 33600 exact

  __shared__ int s_lbl[64];
  __shared__ float s_iou[64];

  if (t < 64) {
    const int a = row0 + t;
    const int i = b * MM + a;
    const unsigned int c = cnt[i];
    int g = 0;
    const bool fg = (c != 0u);
    if (c == 1u) {
      g = (int)gidx[i];
    } else if (c > 1u) {
      // reference: column replaced by one_hot(argmax_g overlaps) — includes
      // masked gts; first-max tie-break like jnp.argmax.
      const float4 ab = anchors[a];
      float best = -1.0f;
      for (int gg = 0; gg < NGT; ++gg) {
        const float ovv = iou_f(gtb[b * NGT + gg], ab);
        if (ovv > best) { best = ovv; g = gg; }
      }
    }
    const int lbl = fg ? glabels[b * NGT + g] : BGI;
    out_labels[i] = (float)lbl;
    out_bbox[i] = gtb[b * NGT + g];  // !fg -> g==0 (argmax of zeros)
    const float io = fg ? iou_f(gtb[b * NGT + g], predb[i]) : 0.0f;
    out_fg[i] = fg ? 1.0f : 0.0f;
    s_lbl[t] = fg ? lbl : -1;
    s_iou[t] = io;
  }
  __syncthreads();

  // 64 rows * 20 float4 = 1280 float4; 320 threads * 4 iters, coalesced.
  const size_t base = ((size_t)b * MM + row0) * 20;
#pragma unroll
  for (int it = 0; it < 4; ++it) {
    const int idx = it * 320 + t;
    const int row = idx / 20;          // magic-mul, compile-time const 20
    const int c4 = idx - row * 20;
    const int lbl = s_lbl[row];
    const float io = s_iou[row];
    const int cb = c4 * 4;
    float4 v;
    v.x = (lbl == cb) ? io : 0.0f;
    v.y = (lbl == cb + 1) ? io : 0.0f;
    v.z = (lbl == cb + 2) ? io : 0.0f;
    v.w = (lbl == cb + 3) ? io : 0.0f;
    out_scores[base + idx] = v;
  }
}

extern "C" void kernel_launch(void* const* d_in, const int* in_sizes, int n_in,
                              void* d_out, int out_size, void* d_ws, size_t ws_size,
                              hipStream_t stream) {
  // Identify inputs by size (robust to how the n_level tuple is passed).
  const float* anchors = nullptr;
  const float* gtb = nullptr;
  const int* glab = nullptr;
  const float* maskgt = nullptr;
  const float* predb = nullptr;
  int seen512 = 0;
  for (int i = 0; i < n_in; ++i) {
    const int sz = in_sizes[i];
    if (sz == 134400 && !anchors) anchors = (const float*)d_in[i];
    else if (sz == 2048 && !gtb) gtb = (const float*)d_in[i];
    else if (sz == 512) {
      if (seen512++ == 0) glab = (const int*)d_in[i];
      else maskgt = (const float*)d_in[i];
    } else if (sz == 2150400 && !predb) predb = (const float*)d_in[i];
  }
  if (!anchors || !gtb || !glab || !maskgt || !predb) return;  // defensive

  float* out = (float*)d_out;
  float* out_labels = out;                          // [B*M]
  float4* out_bbox = (float4*)(out + 537600);       // [B*M][4]
  float4* out_scores = (float4*)(out + 2688000);    // [B*M][80]
  float* out_fg = out + 45696000;                   // [B*M]

  unsigned int* cnt = (unsigned int*)d_ws;          // [B*M]
  unsigned int* gidx = cnt + 537600;                // [B*M]
  float2* centers = (float2*)(gidx + 537600);       // [M], 8B-aligned

  k_prep<<<dim3(2100), dim3(256), 0, stream>>>(
      (const float4*)anchors, centers, cnt);

  k_topk<<<dim3(BB * NGT), dim3(1024), 0, stream>>>(
      (const float4*)anchors, centers, (const float4*)gtb, maskgt, cnt, gidx);

  k_out<<<dim3(525, BB), dim3(320), 0, stream>>>(
      (const float4*)anchors, (const float4*)gtb, glab, (const float4*)predb,
      cnt, gidx, out_labels, out_bbox, out_fg, out_scores);
}